// Round 4
// baseline (118.466 us; speedup 1.0000x reference)
//
#include <hip/hip_runtime.h>

// YOLO-v1 style loss on MI355X (gfx950).
// Inputs: d_in[0] = output (BATCH*S*S*30 fp32), d_in[1] = target (same).
// Outputs: d_out[0..2] = (loss, sum_iou, acc) as fp32.
//
// R5 post-mortem: persistent 1-block/CU double-buffered counted-vmcnt
// pipeline got ~30us (2x the 15.3us BW floor). With one barrier-locked
// block per CU every vmcnt stall idles the whole CU, and the compiler may
// conservatively drain vmcnt before ds_reads it can't disambiguate from
// in-flight global_load_lds writes.
// R6: many small ONE-SHOT blocks instead of a hand pipeline. 128 threads,
// 128 cells, 30.7KB LDS -> 5 blocks/CU, 10 waves/CU, 3136 blocks. Each
// block: global_load_lds stage (coalesced 1KB/instr), one __syncthreads,
// compute, wave reduce, one partial store. Block-level interleave (m114)
// hides each block's drain bubble with the other 4 blocks' traffic --
// no inline asm, nothing for the compiler to pessimize.
// (R6 resubmit: previous run died to a container-acquire flake, not the
// kernel; audit found no hang/correctness hazard.)

#define NACC 8
#define CELLS 128
#define TPB 128
#define TILE_FLOATS (CELLS * 30)        // 3840 floats = 15360 B per array
#define TILE_CHUNKS (TILE_FLOATS / 4)   // 960 float4 chunks per array

__device__ __forceinline__ float wave_reduce_sum(float v) {
    #pragma unroll
    for (int off = 32; off > 0; off >>= 1)
        v += __shfl_down(v, off, 64);
    return v;
}

__device__ __forceinline__ void gld16(const float4* g, float4* l) {
    __builtin_amdgcn_global_load_lds(
        (const __attribute__((address_space(1))) void*)g,
        (__attribute__((address_space(3))) void*)l, 16, 0, 0);
}

// Per-cell loss contributions; o/t are 30 floats with compile-time indices.
__device__ __forceinline__ void cell_loss(const float* __restrict__ o,
                                          const float* __restrict__ t,
                                          float v[NACC]) {
    const float m = (t[4] > 0.f) ? 1.f : 0.f;

    const float txc = t[0] / 7.f, tyc = t[1] / 7.f;
    const float tx0 = txc - 0.5f * t[2], ty0 = tyc - 0.5f * t[3];
    const float tx1 = txc + 0.5f * t[2], ty1 = tyc + 0.5f * t[3];
    const float at  = (tx1 - tx0) * (ty1 - ty0);

    float iou[2];
    #pragma unroll
    for (int b = 0; b < 2; b++) {
        const float bx = o[5 * b + 0], by = o[5 * b + 1];
        const float bw = o[5 * b + 2], bh = o[5 * b + 3];
        const float xc = bx / 7.f, yc = by / 7.f;
        const float x0 = xc - 0.5f * bw, y0 = yc - 0.5f * bh;
        const float x1 = xc + 0.5f * bw, y1 = yc + 0.5f * bh;
        const float ap = (x1 - x0) * (y1 - y0);
        const float wi = fmaxf(fminf(x1, tx1) - fmaxf(x0, tx0), 0.f);
        const float hi = fmaxf(fminf(y1, ty1) - fmaxf(y0, ty0), 0.f);
        const float inter = wi * hi;
        iou[b] = inter / (ap + at - inter);
    }

    // first-max tie-break: box 1 responsible only if STRICTLY greater
    const bool  r1      = iou[1] > iou[0];
    const float max_iou = fmaxf(iou[0], iou[1]);
    const float min_iou = fminf(iou[0], iou[1]);
    const float rb0 = r1 ? o[5] : o[0];
    const float rb1 = r1 ? o[6] : o[1];
    const float rb2 = r1 ? o[7] : o[2];
    const float rb3 = r1 ? o[8] : o[3];
    const float rb4 = r1 ? o[9] : o[4];
    const float nb4 = r1 ? o[4] : o[9];

    {
        const float dx = rb0 - t[0];
        const float dy = rb1 - t[1];
        const float dw = sqrtf(rb2) - sqrtf(t[2]);
        const float dh = sqrtf(rb3) - sqrtf(t[3]);
        v[1] += m * (dx * dx + dy * dy + dw * dw + dh * dh);
    }
    {
        const float d = rb4 - max_iou;
        v[2] += m * d * d;
    }
    v[3] += m * nb4 * nb4;
    {
        const float d0 = o[4] - t[4];
        const float d1 = o[9] - t[9];
        v[4] += (1.f - m) * (d0 * d0 + d1 * d1);
    }

    float cls_sum = 0.f;
    int   oarg = 0, targ = 0;
    float obest = o[10], tbest = t[10];
    #pragma unroll
    for (int c = 0; c < 20; c++) {
        const float oc = o[10 + c], tc = t[10 + c];
        const float d = oc - tc;
        cls_sum += d * d;
        if (oc > obest) { obest = oc; oarg = c; }
        if (tc > tbest) { tbest = tc; targ = c; }
    }
    v[5] += m * cls_sum;
    v[6] += m * min_iou;
    v[7] += (m > 0.f && oarg == targ) ? 1.f : 0.f;
    v[0] += m;
}

__global__ __launch_bounds__(TPB) void yolo_loss_kernel(
        const float* __restrict__ out,
        const float* __restrict__ tgt,
        float* __restrict__ partials, int N) {
    __shared__ float sA[TILE_FLOATS];   // 15360 B
    __shared__ float sB[TILE_FLOATS];   // 15360 B
    __shared__ float sred[2][NACC];

    const int tid   = threadIdx.x;
    const int tile0 = blockIdx.x * CELLS;
    const int cells = min(CELLS, N - tile0);

    float v[NACC];
    #pragma unroll
    for (int k = 0; k < NACC; k++) v[k] = 0.f;

    if (cells == CELLS) {
        // full tile: direct-to-LDS staging, 15 x 1KB coalesced per wave
        const float4* gA = (const float4*)(out + (size_t)tile0 * 30);
        const float4* gB = (const float4*)(tgt + (size_t)tile0 * 30);
        float4* lA = (float4*)sA;
        float4* lB = (float4*)sB;
        #pragma unroll
        for (int j = 0; j < 7; j++) {
            const int c = j * TPB + tid;
            gld16(gA + c, lA + c);
        }
        if (tid < 64) gld16(gA + 896 + tid, lA + 896 + tid);
        #pragma unroll
        for (int j = 0; j < 7; j++) {
            const int c = j * TPB + tid;
            gld16(gB + c, lB + c);
        }
        if (tid >= 64) gld16(gB + 896 + (tid - 64), lB + 896 + (tid - 64));
        __syncthreads();   // drains vmcnt(0): gld16 LDS writes complete

        float o[30], t[30];
        const float2* a2 = (const float2*)(sA + tid * 30);
        const float2* b2 = (const float2*)(sB + tid * 30);
        #pragma unroll
        for (int k = 0; k < 15; k++) {
            const float2 xa = a2[k];
            o[2 * k] = xa.x; o[2 * k + 1] = xa.y;
            const float2 xb = b2[k];
            t[2 * k] = xb.x; t[2 * k + 1] = xb.y;
        }
        cell_loss(o, t, v);
    } else if (tid < cells) {
        // tail tile: direct (uncoalesced but tiny: <128 cells once)
        float o[30], t[30];
        const size_t cb = (size_t)(tile0 + tid) * 30;
        const float2* a2 = (const float2*)(out + cb);
        const float2* b2 = (const float2*)(tgt + cb);
        #pragma unroll
        for (int k = 0; k < 15; k++) {
            const float2 xa = a2[k];
            o[2 * k] = xa.x; o[2 * k + 1] = xa.y;
            const float2 xb = b2[k];
            t[2 * k] = xb.x; t[2 * k + 1] = xb.y;
        }
        cell_loss(o, t, v);
    }

    // 2-wave block reduce -> one plain store set per block (no atomics)
    const int lane = tid & 63;
    const int wid  = tid >> 6;
    #pragma unroll
    for (int k = 0; k < NACC; k++) v[k] = wave_reduce_sum(v[k]);
    if (cells != CELLS) __syncthreads();  // tail path: uniform, harmless
    if (lane == 0) {
        #pragma unroll
        for (int k = 0; k < NACC; k++) sred[wid][k] = v[k];
    }
    __syncthreads();
    if (tid < NACC) {
        const int k = tid;
        partials[(size_t)blockIdx.x * NACC + k] = sred[0][k] + sred[1][k];
    }
}

__global__ __launch_bounds__(256) void yolo_finalize_kernel(
        const float* __restrict__ partials,
        float* __restrict__ res, int N, int rows) {
    __shared__ float sred[4][NACC];
    float v[NACC];
    #pragma unroll
    for (int k = 0; k < NACC; k++) v[k] = 0.f;

    for (int b = threadIdx.x; b < rows; b += 256) {
        #pragma unroll
        for (int k = 0; k < NACC; k++)
            v[k] += partials[(size_t)b * NACC + k];
    }

    const int lane = threadIdx.x & 63;
    const int wid  = threadIdx.x >> 6;
    #pragma unroll
    for (int k = 0; k < NACC; k++) v[k] = wave_reduce_sum(v[k]);
    if (lane == 0) {
        #pragma unroll
        for (int k = 0; k < NACC; k++) sred[wid][k] = v[k];
    }
    __syncthreads();
    if (threadIdx.x == 0) {
        float acc[NACC];
        #pragma unroll
        for (int k = 0; k < NACC; k++)
            acc[k] = sred[0][k] + sred[1][k] + sred[2][k] + sred[3][k];
        const float n_obj   = acc[0];
        const float n_noobj = (float)N - n_obj;
        const float contain     = acc[1] / (2.f * n_obj);
        const float obj_loss    = acc[2] / n_obj;
        const float not_contain = acc[3] / n_obj;
        const float noobj_loss  = acc[4] / (2.f * n_noobj);
        const float class_loss  = acc[5] / (n_obj * 20.f);
        res[0] = 5.f * contain + obj_loss
               + 0.5f * (noobj_loss + not_contain) + class_loss;
        res[1] = acc[6];
        res[2] = acc[7];
    }
}

extern "C" void kernel_launch(void* const* d_in, const int* in_sizes, int n_in,
                              void* d_out, int out_size, void* d_ws, size_t ws_size,
                              hipStream_t stream) {
    const float* out_p = (const float*)d_in[0];
    const float* tgt_p = (const float*)d_in[1];
    float* ws  = (float*)d_ws;   // blocks*NACC partial sums
    float* res = (float*)d_out;
    const int N = in_sizes[0] / 30;        // 8192*7*7 = 401408 cells
    int blocks = (N + CELLS - 1) / CELLS;  // 3136 for N=401408
    if (blocks < 1) blocks = 1;

    yolo_loss_kernel<<<blocks, TPB, 0, stream>>>(out_p, tgt_p, ws, N);
    yolo_finalize_kernel<<<1, 256, 0, stream>>>(ws, res, N, blocks);
}